// Round 10
// baseline (325.327 us; speedup 1.0000x reference)
//
#include <hip/hip_runtime.h>

// LoRALinear: out[8192,4096] = x @ W.T + 2.0*(x@A.T)@B.T = x @ (W + 2*B@A).T
// One bf16 MFMA GEMM, 256x256 tile, 8 waves, BK=32, FOUR LDS buffers,
// cross-body fragment lookahead: body t MFMAs frags(t) [read in body t-1],
// reads frags(t+1), stages tile t+3. One barrier + vmcnt(4) per body.

#define N_ROWS 8192
#define K_DIM  4096
#define N_COLS 4096
#define RANK   16
#define BK     32
#define NT     (K_DIM / BK)   // 128 K-bodies

#define XBLK ((N_ROWS * K_DIM / 4) / 256)   // 32768 blocks for x->bf16
#define WBLK ((N_COLS * K_DIM / 4) / 256)   // 16384 blocks for W_eff->bf16

typedef __bf16 bf16x8 __attribute__((ext_vector_type(8)));
typedef float  f32x4  __attribute__((ext_vector_type(4)));

__device__ __forceinline__ unsigned short f2bf(float f) {
  unsigned int u = __builtin_bit_cast(unsigned int, f);
  u += 0x7FFFu + ((u >> 16) & 1u);   // RNE
  return (unsigned short)(u >> 16);
}

// ---------------- fused conversion kernel ----------------

__global__ __launch_bounds__(256) void prep_kernel(const float* __restrict__ x,
                                                   const float* __restrict__ w,
                                                   const float* __restrict__ A,
                                                   const float* __restrict__ Bm,
                                                   unsigned short* __restrict__ xb,
                                                   unsigned short* __restrict__ wb) {
  const int b = blockIdx.x;
  if (b < XBLK) {
    size_t idx = (size_t)b * 256 + threadIdx.x;
    const float4 v = *reinterpret_cast<const float4*>(x + idx * 4);
    ushort4 r;
    r.x = f2bf(v.x); r.y = f2bf(v.y); r.z = f2bf(v.z); r.w = f2bf(v.w);
    *reinterpret_cast<ushort4*>(xb + idx * 4) = r;
  } else {
    size_t idx = (size_t)(b - XBLK) * 256 + threadIdx.x;
    int o  = (int)(idx >> 10);
    int ic = (int)(idx & 1023) << 2;
    const float4 wv = *reinterpret_cast<const float4*>(w + (size_t)o * K_DIM + ic);
    float a0 = wv.x, a1 = wv.y, a2 = wv.z, a3 = wv.w;
    float br[RANK];
#pragma unroll
    for (int r4 = 0; r4 < RANK / 4; ++r4) {
      const float4 bv = *reinterpret_cast<const float4*>(Bm + (size_t)o * RANK + r4 * 4);
      br[r4 * 4 + 0] = bv.x; br[r4 * 4 + 1] = bv.y;
      br[r4 * 4 + 2] = bv.z; br[r4 * 4 + 3] = bv.w;
    }
#pragma unroll
    for (int r = 0; r < RANK; ++r) {
      const float4 av = *reinterpret_cast<const float4*>(A + (size_t)r * K_DIM + ic);
      float b2 = br[r] * 2.0f;
      a0 += b2 * av.x; a1 += b2 * av.y; a2 += b2 * av.z; a3 += b2 * av.w;
    }
    ushort4 rr;
    rr.x = f2bf(a0); rr.y = f2bf(a1); rr.z = f2bf(a2); rr.w = f2bf(a3);
    *reinterpret_cast<ushort4*>(wb + (size_t)o * K_DIM + ic) = rr;
  }
}

// ---------------- GEMM ----------------
// LDS: 4 bufs x 32KB: buf k: A(16KB: 256r x 32k) at k*32768, B at +16384.
// Swizzle within A/B region: row R, k-granule lk (16B): pair p=R>>1, b=R&1,
// phys_slot = ((b<<2)|lk) ^ (p&7); byte = p*128 + phys_slot*16.
// Staged via pre-swizzled global source (linear gload_lds dest).
// Read bases match C-write decomposition: A row = mf*32+wr*16+lr ->
// a_base = mf*2048 + wr*1024 + (lr>>1)*128 + slot*16 (p&7 = lr>>1);
// B row = nf*64+wc*16+lr -> b_base = nf*4096 + wc*1024 + same lane term.

__device__ __forceinline__ void gload_lds16(const void* g, void* l) {
  __builtin_amdgcn_global_load_lds(
      (__attribute__((address_space(1))) void*)g,
      (__attribute__((address_space(3))) void*)l, 16, 0, 0);
}

__global__ __launch_bounds__(512, 1) void gemm_bf16_r10(
    const unsigned short* __restrict__ xb, const unsigned short* __restrict__ wb,
    float* __restrict__ out) {
  __shared__ __align__(16) char smem[131072];

  const int t  = threadIdx.x;
  const int l  = t & 63;
  const int wv = t >> 6;
  const int lr = l & 15;
  const int lk = l >> 4;
  const int wr = wv >> 2;     // 0..1
  const int wc = wv & 3;      // 0..3

  // XCD-aware bijective swizzle: 512 blocks % 8 == 0
  const int bid  = blockIdx.x;
  const int sbid = (bid & 7) * 64 + (bid >> 3);
  const int bm   = sbid >> 4;   // 0..31
  const int bn   = sbid & 15;   // 0..15

  // ---- staging source (pre-swizzled): thread t fills phys granule t of an
  // 8KB half-region (128 rows); logical slot = (t&7)^((t>>3)&7)
  const int slog  = (t & 7) ^ ((t >> 3) & 7);
  const int s_row = 2 * (t >> 3) + (slog >> 2);    // 0..127
  const int s_k   = (slog & 3) * 8;                // 0,8,16,24
  const unsigned short* gA = xb + (size_t)(bm * 256 + s_row) * K_DIM + s_k;
  const unsigned short* gB = wb + (size_t)(bn * 256 + s_row) * K_DIM + s_k;

#define STG_A(BUFB, KT) do {                                                    \
    const unsigned short* _g = gA + (size_t)(KT) * BK;                          \
    char* _l = smem + (BUFB) + t * 16;                                          \
    gload_lds16(_g, _l);                                                        \
    gload_lds16(_g + (size_t)128 * K_DIM, _l + 8192);                           \
  } while (0)
#define STG_B(BUFB, KT) do {                                                    \
    const unsigned short* _g = gB + (size_t)(KT) * BK;                          \
    char* _l = smem + (BUFB) + 16384 + t * 16;                                  \
    gload_lds16(_g, _l);                                                        \
    gload_lds16(_g + (size_t)128 * K_DIM, _l + 8192);                           \
  } while (0)

  // ---- fragment read addressing (matching swizzle; p&7 == lr>>1) ----
  const int lane_off = (lr >> 1) * 128 + (((((lr & 1) << 2) | lk) ^ (lr >> 1)) << 4);
  const int a_base = wr * 1024 + lane_off;          // + mf*2048
  const int b_base = 16384 + wc * 1024 + lane_off;  // + nf*4096

  bf16x8 sA0[8], sB0[4], sA1[8], sB1[4];
  f32x4 acc[8][4];
#pragma unroll
  for (int m = 0; m < 8; ++m)
#pragma unroll
    for (int n = 0; n < 4; ++n)
      acc[m][n] = (f32x4){0.f, 0.f, 0.f, 0.f};

#define RD_SET(SA, SB, RB) do {                                                 \
    _Pragma("unroll")                                                           \
    for (int m = 0; m < 8; ++m)                                                 \
      SA[m] = *(const bf16x8*)(smem + (RB) + a_base + m * 2048);                \
    _Pragma("unroll")                                                           \
    for (int n = 0; n < 4; ++n)                                                 \
      SB[n] = *(const bf16x8*)(smem + (RB) + b_base + n * 4096);                \
  } while (0)

#define MF_SET(SA, SB) do {                                                     \
    _Pragma("unroll")                                                           \
    for (int m = 0; m < 8; ++m)                                                 \
      _Pragma("unroll")                                                         \
      for (int n = 0; n < 4; ++n)                                               \
        acc[m][n] = __builtin_amdgcn_mfma_f32_16x16x32_bf16(                    \
            SA[m], SB[n], acc[m][n], 0, 0, 0);                                  \
  } while (0)

// body t: stage(t+3)->SB_OFF, read frags(t+1)->next set from RB_OFF,
// MFMA on current set, vmcnt(4) [confirms stage(t+2)], barrier.
#define BODY(RB_OFF, SB_OFF, CUR_A, CUR_B, NXT_A, NXT_B, TT) do {               \
    const int _ts = ((TT) + 3 < NT) ? (TT) + 3 : NT - 1;                        \
    STG_A(SB_OFF, _ts); STG_B(SB_OFF, _ts);                                     \
    RD_SET(NXT_A, NXT_B, RB_OFF);                                               \
    __builtin_amdgcn_s_setprio(1);                                              \
    MF_SET(CUR_A, CUR_B);                                                       \
    __builtin_amdgcn_s_setprio(0);                                              \
    __builtin_amdgcn_sched_barrier(0);                                          \
    asm volatile("s_waitcnt vmcnt(4)");                                         \
    __builtin_amdgcn_s_barrier();                                               \
    __builtin_amdgcn_sched_barrier(0);                                          \
  } while (0)

  // ---- prologue: stage tiles 0,1,2 -> bufs 0,1,2; confirm 0,1; read frags(0)
  STG_A(0, 0);      STG_B(0, 0);
  STG_A(32768, 1);  STG_B(32768, 1);
  STG_A(65536, 2);  STG_B(65536, 2);
  __builtin_amdgcn_sched_barrier(0);
  asm volatile("s_waitcnt vmcnt(4)");
  __builtin_amdgcn_s_barrier();
  __builtin_amdgcn_sched_barrier(0);
  RD_SET(sA0, sB0, 0);

  // bodies t = 4u+i: cbuf=t&3, rbuf=(t+1)&3, sbuf=(t+3)&3; set parity t&1
#pragma nounroll
  for (int u = 0; u < NT / 4; ++u) {
    const int tb = 4 * u;
    BODY(32768, 98304, sA0, sB0, sA1, sB1, tb);        // t%4=0: r1 s3 c:set0
    BODY(65536, 0,     sA1, sB1, sA0, sB0, tb + 1);    // t%4=1: r2 s0 c:set1
    BODY(98304, 32768, sA0, sB0, sA1, sB1, tb + 2);    // t%4=2: r3 s1 c:set0
    BODY(0,     65536, sA1, sB1, sA0, sB0, tb + 3);    // t%4=3: r0 s2 c:set1
  }

  // ---- epilogue: C/D layout col=lane&15, row=(lane>>4)*4+j ----
  const int orow = bm * 256 + wr * 16 + lk * 4;
  const int ocol = bn * 256 + wc * 16 + lr;
#pragma unroll
  for (int mf = 0; mf < 8; ++mf)
#pragma unroll
    for (int nf = 0; nf < 4; ++nf)
#pragma unroll
      for (int j = 0; j < 4; ++j)
        out[(size_t)(orow + mf * 32 + j) * N_COLS + (ocol + nf * 64)] = acc[mf][nf][j];

#undef STG_A
#undef STG_B
#undef RD_SET
#undef MF_SET
#undef BODY
}

// ---------------- exact fp32 fallback (ws too small) ----------------

__global__ __launch_bounds__(256) void fallback_kernel(const float* __restrict__ x,
                                                       const float* __restrict__ w,
                                                       const float* __restrict__ A,
                                                       const float* __restrict__ Bm,
                                                       float* __restrict__ out) {
  const int o    = blockIdx.x * 256 + threadIdx.x;
  const int nrow = blockIdx.y;
  float bro[RANK];
#pragma unroll
  for (int r = 0; r < RANK; ++r) bro[r] = Bm[(size_t)o * RANK + r] * 2.0f;
  float bacc = 0.f;
  float tacc[RANK];
#pragma unroll
  for (int r = 0; r < RANK; ++r) tacc[r] = 0.f;
  for (int k = 0; k < K_DIM; ++k) {
    float xv = x[(size_t)nrow * K_DIM + k];
    bacc += xv * w[(size_t)o * K_DIM + k];
#pragma unroll
    for (int r = 0; r < RANK; ++r) tacc[r] += xv * A[(size_t)r * K_DIM + k];
  }
  float res = bacc;
#pragma unroll
  for (int r = 0; r < RANK; ++r) res += bro[r] * tacc[r];
  out[(size_t)nrow * N_COLS + o] = res;
}

// ---------------- launch ----------------

extern "C" void kernel_launch(void* const* d_in, const int* in_sizes, int n_in,
                              void* d_out, int out_size, void* d_ws, size_t ws_size,
                              hipStream_t stream) {
  const float* x  = (const float*)d_in[0];
  const float* w  = (const float*)d_in[1];
  const float* A  = (const float*)d_in[2];
  const float* Bm = (const float*)d_in[3];
  float* out = (float*)d_out;

  const size_t need = ((size_t)N_ROWS * K_DIM + (size_t)N_COLS * K_DIM) * sizeof(unsigned short);
  if (ws_size < need) {
    dim3 grid(N_COLS / 256, N_ROWS);
    fallback_kernel<<<grid, 256, 0, stream>>>(x, w, A, Bm, out);
    return;
  }

  unsigned short* xb = (unsigned short*)d_ws;
  unsigned short* wb = xb + (size_t)N_ROWS * K_DIM;

  prep_kernel<<<XBLK + WBLK, 256, 0, stream>>>(x, w, A, Bm, xb, wb);

  const int grid_gemm = (N_ROWS / 256) * (N_COLS / 256);   // 512
  gemm_bf16_r10<<<grid_gemm, 512, 0, stream>>>(xb, wb, out);
}